// Round 5
// baseline (1916.975 us; speedup 1.0000x reference)
//
#include <hip/hip_runtime.h>
#include <cstdio>
#include <cstdint>

// Problem constants (from setup_inputs; fixed for this problem)
#define TOK   32760      // N_t * S
#define DIM   1536
#define ENCD  768
#define NA    32
#define NT    21
#define SS    1560
#define HEADS 12
#define HD    128
#define KVROWS (NT * NA)   // 672

using f32x4  = __attribute__((ext_vector_type(4))) float;
using bf16x8 = __attribute__((ext_vector_type(8))) short;

__device__ __forceinline__ ushort bf16hi(float f) {
  unsigned u = __float_as_uint(f);
  return (ushort)((u + 0x7FFFu + ((u >> 16) & 1u)) >> 16);   // RNE
}
__device__ __forceinline__ float bf16tof(ushort h) {
  return __uint_as_float(((unsigned)h) << 16);
}

__device__ __forceinline__ void gload16(const void* g, void* l) {
  __builtin_amdgcn_global_load_lds((const __attribute__((address_space(1))) void*)g,
                                   (__attribute__((address_space(3))) void*)l,
                                   16, 0, 0);
}

// ---------------------------------------------------------------------------
// 1) min/max of the two attn-map rows + per-token rotary position
// ---------------------------------------------------------------------------
__global__ __launch_bounds__(1024) void minmax_pos_kernel(
    const float* __restrict__ m, float* __restrict__ pos, int N) {
  __shared__ float red[4][16];
  __shared__ float fin[4];
  int tid = threadIdx.x;
  float mn0 = 3.4e38f, mx0 = -3.4e38f, mn1 = 3.4e38f, mx1 = -3.4e38f;
  for (int i = tid; i < N; i += 1024) {
    float a = m[i], b = m[N + i];
    mn0 = fminf(mn0, a); mx0 = fmaxf(mx0, a);
    mn1 = fminf(mn1, b); mx1 = fmaxf(mx1, b);
  }
  #pragma unroll
  for (int o = 32; o >= 1; o >>= 1) {
    mn0 = fminf(mn0, __shfl_xor(mn0, o)); mx0 = fmaxf(mx0, __shfl_xor(mx0, o));
    mn1 = fminf(mn1, __shfl_xor(mn1, o)); mx1 = fmaxf(mx1, __shfl_xor(mx1, o));
  }
  int wid = tid >> 6, ln = tid & 63;
  if (ln == 0) { red[0][wid] = mn0; red[1][wid] = mx0; red[2][wid] = mn1; red[3][wid] = mx1; }
  __syncthreads();
  if (tid == 0) {
    float a = red[0][0], b = red[1][0], c = red[2][0], d = red[3][0];
    for (int i = 1; i < 16; i++) {
      a = fminf(a, red[0][i]); b = fmaxf(b, red[1][i]);
      c = fminf(c, red[2][i]); d = fmaxf(d, red[3][i]);
    }
    fin[0] = a; fin[1] = b; fin[2] = c; fin[3] = d;
  }
  __syncthreads();
  float mn0f = fin[0], sc0 = 4.0f / (fin[1] - fin[0] + 1e-8f);
  float mn1f = fin[2], sc1 = 4.0f / (fin[3] - fin[2] + 1e-8f);
  for (int i = tid; i < N; i += 1024) {
    float a = m[i], b = m[N + i];
    float h1 = (a - mn0f) * sc0;            // [0,4]
    float h2 = (b - mn1f) * sc1 + 20.0f;    // [20,24]
    pos[i] = (a >= b) ? h1 : h2;
  }
}

// ---------------------------------------------------------------------------
// 2) fp32 -> (bf16 hi | bf16 lo) split, rows of length K -> rows of length 2K
// ---------------------------------------------------------------------------
__global__ void conv_hilo_kernel(const float* __restrict__ in, ushort* __restrict__ out,
                                 int M, int K) {
  int total4 = M * (K / 4);
  for (int idx = blockIdx.x * blockDim.x + threadIdx.x; idx < total4;
       idx += gridDim.x * blockDim.x) {
    int e = idx * 4;
    int row = e / K;
    int k = e - row * K;
    float4 v = *(const float4*)(in + e);
    float fs[4] = {v.x, v.y, v.z, v.w};
    ushort hs[4], ls[4];
    #pragma unroll
    for (int t = 0; t < 4; t++) {
      hs[t] = bf16hi(fs[t]);
      float hf = bf16tof(hs[t]);
      ls[t] = bf16hi(fs[t] - hf);
    }
    ushort* po = out + (size_t)row * (2 * K) + k;
    *(ushort4*)(po)     = make_ushort4(hs[0], hs[1], hs[2], hs[3]);
    *(ushort4*)(po + K) = make_ushort4(ls[0], ls[1], ls[2], ls[3]);
  }
}

// ---------------------------------------------------------------------------
// 3a) OLD 128x128 1-phase split-bf16 GEMM — kept for the tiny KV GEMM (M=672)
//     where grid fill matters more than per-block efficiency.
// ---------------------------------------------------------------------------
__global__ __launch_bounds__(256, 2) void gemm_bf16s_kernel(
    const ushort* __restrict__ A, const ushort* __restrict__ B,
    const float* __restrict__ bias, float* __restrict__ C,
    int M, int N, int K) {
  __shared__ __align__(16) ushort lAh[128][64];
  __shared__ __align__(16) ushort lAl[128][64];
  __shared__ __align__(16) ushort lBh[128][64];
  __shared__ __align__(16) ushort lBl[128][64];
  const int tid = threadIdx.x;
  const int lane = tid & 63;
  const int w = tid >> 6;
  const int wm = w >> 1, wn = w & 1;
  const int quad = lane >> 4, m16 = lane & 15;
  const int r_off = lane >> 3;
  const int g     = lane & 7;
  const int gg8   = (g ^ r_off) * 8;

  int bx = blockIdx.x, by = blockIdx.y;
  {
    const int nx = gridDim.x, ny = gridDim.y;
    if ((ny & 7) == 0) {
      int flat = by * nx + bx;
      int xcd = flat & 7, s = flat >> 3;
      int panel = s / nx;
      bx = s - panel * nx;
      by = panel * 8 + xcd;
    }
  }
  const int m0 = by * 128, n0 = bx * 128;
  const int lda = 2 * K;

  f32x4 acc[4][4];
  #pragma unroll
  for (int i = 0; i < 4; i++)
    #pragma unroll
    for (int j = 0; j < 4; j++) acc[i][j] = (f32x4){0.f, 0.f, 0.f, 0.f};

  const int nIter = K / 64;
  for (int kt = 0; kt < nIter; kt++) {
    const int kH = kt * 64;
    const int kL = K + kt * 64;
    __syncthreads();
    #pragma unroll
    for (int i = 0; i < 4; i++) {
      const int ss = w * 4 + i;
      int rowA = m0 + ss * 8 + r_off; if (rowA >= M) rowA = M - 1;
      const ushort* ar = A + (size_t)rowA * lda;
      gload16(ar + kH + gg8, (char*)&lAh[0][0] + ss * 1024);
      gload16(ar + kL + gg8, (char*)&lAl[0][0] + ss * 1024);
      int rowB = n0 + ss * 8 + r_off; if (rowB >= N) rowB = N - 1;
      const ushort* br = B + (size_t)rowB * lda;
      gload16(br + kH + gg8, (char*)&lBh[0][0] + ss * 1024);
      gload16(br + kL + gg8, (char*)&lBl[0][0] + ss * 1024);
    }
    __syncthreads();
    #pragma unroll
    for (int kk = 0; kk < 2; kk++) {
      const int slot8 = (((kk * 4 + quad) ^ (m16 & 7)) * 8);
      bf16x8 fah[4], fbh[4], ft[4];
      #pragma unroll
      for (int i = 0; i < 4; i++) {
        fah[i] = *(const bf16x8*)(&lAh[wm * 64 + i * 16 + m16][slot8]);
        fbh[i] = *(const bf16x8*)(&lBh[wn * 64 + i * 16 + m16][slot8]);
      }
      #pragma unroll
      for (int i = 0; i < 4; i++)
        #pragma unroll
        for (int j = 0; j < 4; j++)
          acc[i][j] = __builtin_amdgcn_mfma_f32_16x16x32_bf16(fah[i], fbh[j], acc[i][j], 0, 0, 0);
      #pragma unroll
      for (int i = 0; i < 4; i++)
        ft[i] = *(const bf16x8*)(&lBl[wn * 64 + i * 16 + m16][slot8]);
      #pragma unroll
      for (int i = 0; i < 4; i++)
        #pragma unroll
        for (int j = 0; j < 4; j++)
          acc[i][j] = __builtin_amdgcn_mfma_f32_16x16x32_bf16(fah[i], ft[j], acc[i][j], 0, 0, 0);
      #pragma unroll
      for (int i = 0; i < 4; i++)
        ft[i] = *(const bf16x8*)(&lAl[wm * 64 + i * 16 + m16][slot8]);
      #pragma unroll
      for (int i = 0; i < 4; i++)
        #pragma unroll
        for (int j = 0; j < 4; j++)
          acc[i][j] = __builtin_amdgcn_mfma_f32_16x16x32_bf16(ft[i], fbh[j], acc[i][j], 0, 0, 0);
    }
  }
  #pragma unroll
  for (int j = 0; j < 4; j++) {
    const int col = n0 + wn * 64 + j * 16 + m16;
    const float bv = bias[col];
    #pragma unroll
    for (int i = 0; i < 4; i++) {
      const int rbase = m0 + wm * 64 + i * 16 + quad * 4;
      #pragma unroll
      for (int r = 0; r < 4; r++) {
        const int row = rbase + r;
        if (row < M) C[(size_t)row * N + col] = acc[i][j][r] + bv;
      }
    }
  }
}

// ---------------------------------------------------------------------------
// 3b) 256x256-tile 8-phase split-bf16 GEMM (T3+T4+T5 port of m201).
//
// Geometry: BM=BN=256, BK=32, 8 waves (2M x 4N), per-wave out = 128x64.
// LDS: SA/SB[2 buf][256 rows][128 B], row = hi(32 ush)|lo(32 ush), the eight
// 16-B granules of each row XOR-swizzled by (row&7)  -> ds_read_b128 of a
// fragment column spreads evenly over all 32 banks, and global_load_lds stays
// linear-dest with a pre-swizzled per-lane SOURCE granule (guide rule #21).
//
// Schedule per K-step s (buffer b=s&1), 4 phases; 2 steps = the 8-phase ring:
//   p1 (mh0,nh1): prefetch c3(s+1)=A-h1 -> buf b^1
//   p2 (mh1,nh1): prefetch c4(s+1)=B-nh0 -> buf b^1
//   p3 (mh0,nh0): prefetch c1(s+2)=B-nh1 -> buf b     (region freed after p2)
//   p4 (mh1,nh0): prefetch c2(s+2)=A-h0 -> buf b      (region freed after p3)
// Each phase: {2 gload16, 12 ds_read_b128, s_barrier, setprio(1), 24 MFMA,
// setprio(0), lgkmcnt(0), s_barrier}.  lgkmcnt(0) before the ending barrier
// guarantees every wave's LDS reads completed before any wave's next-phase
// gload can overwrite that region.
// vmcnt(4) once per iteration (before p4's ending barrier): leaves exactly
// the 2 chunks of step s+2 in flight; all step-s+1 chunks retired before any
// wave crosses into iteration s+1.  Chunks are issued 5-6 phases before use.
// Per-wave vmcnt ledger (audited r3): prologue 12 issued, vmcnt(4) keeps
// c1,c2(1); each iter 4->12 outstanding, vmcnt(4) retires step s+1 exactly.
// LDS roofline (audited r4): 12 ds_read_b128 : 24 MFMA per phase -> per CU
// per K-step 393KB LDS reads (~1536cy @256B/clk) vs 931cy MFMA -> ceiling
// MfmaUtil ~61%, same regime as m201's measured 62%.
// ---------------------------------------------------------------------------
__global__ __launch_bounds__(512, 2) void gemm256_bf16s_kernel(
    const ushort* __restrict__ A, const ushort* __restrict__ B,
    const float* __restrict__ bias, float* __restrict__ C,
    int M, int N, int K) {
  __shared__ __align__(16) ushort SA[2][256][64];   // 64 KB
  __shared__ __align__(16) ushort SB[2][256][64];   // 64 KB
  const int tid  = threadIdx.x;
  const int lane = tid & 63;
  const int w    = tid >> 6;            // 0..7
  const int wm   = w >> 2, wn = w & 3;  // 2 x 4 wave grid
  const int quad = lane >> 4, m16 = lane & 15;
  const int rsel = lane >> 3;           // staging: row within 8-row group
  const int q    = (lane & 7) ^ rsel;   // staging: pre-swizzled source granule
  // XCD swizzle: all 6 column-tiles of a row panel land on one XCD's L2
  int bx = blockIdx.x, by = blockIdx.y;
  {
    const int nx = gridDim.x, ny = gridDim.y;
    if ((ny & 7) == 0) {
      int flat = by * nx + bx;
      int xcd = flat & 7, s = flat >> 3;
      int panel = s / nx;
      bx = s - panel * nx;
      by = panel * 8 + xcd;
    }
  }
  const int m0 = by * 256, n0 = bx * 256;
  const int ld   = 2 * K;
  const int qoff = (q & 3) * 8 + (q >> 2) * K;  // hi granules 0-3, lo 4-7
  const int shq  = (quad ^ (m16 & 7)) * 8;      // hi-slot ushort offset; lo = ^32

  auto stageA = [&](int st, int r0) {            // r0: tile row, multiple of 8
    int R = m0 + r0 + rsel; if (R >= M) R = M - 1;
    gload16(A + (size_t)R * ld + qoff + st * 32, &SA[st & 1][r0][0]);
  };
  auto stageB = [&](int st, int r0) {
    int R = n0 + r0 + rsel; if (R >= N) R = N - 1;
    gload16(B + (size_t)R * ld + qoff + st * 32, &SB[st & 1][r0][0]);
  };
  // chunk staging: 16 8-row groups per chunk, 2 per wave (G = 2w, 2w+1)
  auto c1 = [&](int st) {  // B-nh1: rows {32:64, 96:128, 160:192, 224:256}
    int G = 2 * w;
    stageB(st, 32 + (G >> 2) * 64 + (G & 3) * 8); G++;
    stageB(st, 32 + (G >> 2) * 64 + (G & 3) * 8);
  };
  auto c2 = [&](int st) {  // A-h0: rows {0:64, 128:192}
    int G = 2 * w;
    stageA(st, (G & 7) * 8 + (G >> 3) * 128); G++;
    stageA(st, (G & 7) * 8 + (G >> 3) * 128);
  };
  auto c3 = [&](int st) {  // A-h1: rows {64:128, 192:256}
    int G = 2 * w;
    stageA(st, 64 + (G & 7) * 8 + (G >> 3) * 128); G++;
    stageA(st, 64 + (G & 7) * 8 + (G >> 3) * 128);
  };
  auto c4 = [&](int st) {  // B-nh0: rows {0:32, 64:96, 128:160, 192:224}
    int G = 2 * w;
    stageB(st, (G >> 2) * 64 + (G & 3) * 8); G++;
    stageB(st, (G >> 2) * 64 + (G & 3) * 8);
  };

  f32x4 acc[8][4];
  #pragma unroll
  for (int i = 0; i < 8; i++)
    #pragma unroll
    for (int j = 0; j < 4; j++) acc[i][j] = (f32x4){0.f, 0.f, 0.f, 0.f};

  const int nS = K / 32;
  // prologue: step0 fully + c1,c2(step1)  -> matches steady-state queue depth
  c1(0); c2(0); c3(0); c4(0);
  c1(1); c2(1);
  asm volatile("s_waitcnt vmcnt(4)" ::: "memory");
  __builtin_amdgcn_s_barrier();
  asm volatile("" ::: "memory");

#define PHASE(MH, NH, PF)                                                     \
  {                                                                           \
    PF;                                                                       \
    bf16x8 ah[4], al[4], bh[2], bl[2];                                        \
    _Pragma("unroll")                                                         \
    for (int i = 0; i < 4; i++) {                                             \
      const ushort* ar = &SA[bb][wm * 128 + (MH) * 64 + i * 16 + m16][0];     \
      ah[i] = *(const bf16x8*)(ar + shq);                                     \
      al[i] = *(const bf16x8*)(ar + (shq ^ 32));                              \
    }                                                                         \
    _Pragma("unroll")                                                         \
    for (int j = 0; j < 2; j++) {                                             \
      const ushort* br = &SB[bb][wn * 64 + (NH) * 32 + j * 16 + m16][0];      \
      bh[j] = *(const bf16x8*)(br + shq);                                     \
      bl[j] = *(const bf16x8*)(br + (shq ^ 32));                              \
    }                                                                         \
    __builtin_amdgcn_s_barrier();                                             \
    asm volatile("" ::: "memory");                                            \
    __builtin_amdgcn_s_setprio(1);                                            \
    _Pragma("unroll")                                                         \
    for (int i = 0; i < 4; i++)                                               \
      _Pragma("unroll")                                                       \
      for (int j = 0; j < 2; j++)                                             \
        acc[(MH) * 4 + i][(NH) * 2 + j] = __builtin_amdgcn_mfma_f32_16x16x32_bf16( \
            ah[i], bh[j], acc[(MH) * 4 + i][(NH) * 2 + j], 0, 0, 0);          \
    _Pragma("unroll")                                                         \
    for (int i = 0; i < 4; i++)                                               \
      _Pragma("unroll")                                                       \
      for (int j = 0; j < 2; j++)                                             \
        acc[(MH) * 4 + i][(NH) * 2 + j] = __builtin_amdgcn_mfma_f32_16x16x32_bf16( \
            ah[i], bl[j], acc[(MH) * 4 + i][(NH) * 2 + j], 0, 0, 0);          \
    _Pragma("unroll")                                                         \
    for (int i = 0; i < 4; i++)                                               \
      _Pragma("unroll")                                                       \
      for (int j = 0; j < 2; j++)                                             \
        acc[(MH) * 4 + i][(NH) * 2 + j] = __builtin_amdgcn_mfma_f32_16x16x32_bf16( \
            al[i], bh[j], acc[(MH) * 4 + i][(NH) * 2 + j], 0, 0, 0);          \
    __builtin_amdgcn_s_setprio(0);                                            \
  }

  for (int s = 0; s < nS; s++) {
    const int bb = s & 1;
    PHASE(0, 1, if (s + 1 < nS) c3(s + 1));
    asm volatile("s_waitcnt lgkmcnt(0)" ::: "memory");
    __builtin_amdgcn_s_barrier();
    asm volatile("" ::: "memory");
    PHASE(1, 1, if (s + 1 < nS) c4(s + 1));
    asm volatile("s_waitcnt lgkmcnt(0)" ::: "memory");
    __builtin_amdgcn_s_barrier();
    asm volatile("" ::: "memory");
    PHASE(0, 0, if (s + 2 < nS) c1(s + 2));
    asm volatile("s_waitcnt lgkmcnt(0)" ::: "memory");
    __builtin_amdgcn_s_barrier();
    asm volatile("" ::: "memory");
    PHASE(1, 0, if (s + 2 < nS) c2(s + 2));
    asm volatile("s_waitcnt lgkmcnt(0)" ::: "memory");
    if (s + 2 < nS) { asm volatile("s_waitcnt vmcnt(4)" ::: "memory"); }
    else            { asm volatile("s_waitcnt vmcnt(0)" ::: "memory"); }
    __builtin_amdgcn_s_barrier();
    asm volatile("" ::: "memory");
  }
#undef PHASE

  // epilogue: D row=(lane>>4)*4+reg, col=lane&15  [m89-verified layout]
  #pragma unroll
  for (int J = 0; J < 4; J++) {
    const int col = n0 + wn * 64 + J * 16 + m16;
    const float bv = bias[col];
    #pragma unroll
    for (int I = 0; I < 8; I++) {
      const int rbase = m0 + wm * 128 + I * 16 + quad * 4;
      #pragma unroll
      for (int r = 0; r < 4; r++) {
        const int row = rbase + r;
        if (row < M) C[(size_t)row * N + col] = acc[I][J][r] + bv;
      }
    }
  }
}

// ---------------------------------------------------------------------------
// 4) Fused attention: one wave per (t, head, 30-row chunk).
// ---------------------------------------------------------------------------
__global__ __launch_bounds__(64) void attn_kernel(
    const float* __restrict__ q, const float* __restrict__ kv,
    const float* __restrict__ pos, ushort* __restrict__ attA) {
  const int chunk = blockIdx.x;   // 0..51
  const int head  = blockIdx.y;   // 0..11
  const int t     = blockIdx.z;   // 0..20
  const int lane  = threadIdx.x;  // 0..63
  const int a = lane & 31, h = lane >> 5;
  const float L2_10000_64 = 13.287712379549449f / 64.0f;  // log2(10000)/64

  float kreg[64];
  const float* krow = kv + (size_t)(t * NA + a) * (2 * DIM) + head * HD + h * 64;
  #pragma unroll
  for (int j = 0; j < 16; j++) ((float4*)kreg)[j] = ((const float4*)krow)[j];
  const float pk = (a < 16) ? 2.0f : 22.0f;
  #pragma unroll
  for (int j = 0; j < 32; j++) {
    int ip = h * 32 + j;
    float fr = exp2f(-(float)ip * L2_10000_64);
    float sn, cs; sincosf(pk * fr, &sn, &cs);
    float x0 = kreg[2 * j], x1 = kreg[2 * j + 1];
    kreg[2 * j]     = x0 * cs - x1 * sn;
    kreg[2 * j + 1] = x1 * cs + x0 * sn;
  }
  float vr0[32], vr1[32];
  const float* vbase = kv + (size_t)(t * NA) * (2 * DIM) + DIM + head * HD;
  #pragma unroll
  for (int aa = 0; aa < 32; aa++) {
    vr0[aa] = vbase[(size_t)aa * (2 * DIM) + lane];
    vr1[aa] = vbase[(size_t)aa * (2 * DIM) + 64 + lane];
  }

  __shared__ float qs[128];
  __shared__ float Ps[32];
  const float myfreq = exp2f(-(float)lane * L2_10000_64);

  for (int r = 0; r < 30; r++) {
    const int n = t * SS + chunk * 30 + r;
    float2 qp = ((const float2*)(q + (size_t)n * DIM + head * HD))[lane];
    float p = pos[n];
    float sn, cs; sincosf(p * myfreq, &sn, &cs);
    qs[2 * lane]     = qp.x * cs - qp.y * sn;
    qs[2 * lane + 1] = qp.y * cs + qp.x * sn;
    __syncthreads();
    float accd = 0.f;
    #pragma unroll
    for (int j4 = 0; j4 < 16; j4++) {
      float4 qq = ((const float4*)(qs + h * 64))[j4];
      accd += qq.x * kreg[j4 * 4] + qq.y * kreg[j4 * 4 + 1] +
              qq.z * kreg[j4 * 4 + 2] + qq.w * kreg[j4 * 4 + 3];
    }
    accd += __shfl_xor(accd, 32);
    accd *= 0.08838834764831845f;    // 1/sqrt(128)
    float mx = accd;
    #pragma unroll
    for (int o = 16; o >= 1; o >>= 1) mx = fmaxf(mx, __shfl_xor(mx, o));
    float e = __expf(accd - mx);
    float sum = e;
    #pragma unroll
    for (int o = 16; o >= 1; o >>= 1) sum += __shfl_xor(sum, o);
    float P = e / sum;
    if (lane < 32) Ps[lane] = P;
    __syncthreads();
    float o0 = 0.f, o1 = 0.f;
    #pragma unroll
    for (int aa = 0; aa < 32; aa++) {
      float pa = Ps[aa];
      o0 += pa * vr0[aa];
      o1 += pa * vr1[aa];
    }
    size_t base = (size_t)n * (2 * DIM);
    int c0 = head * HD + lane;
    ushort h0 = bf16hi(o0); ushort l0 = bf16hi(o0 - bf16tof(h0));
    ushort h1 = bf16hi(o1); ushort l1 = bf16hi(o1 - bf16tof(h1));
    attA[base + c0]            = h0;
    attA[base + DIM + c0]      = l0;
    attA[base + c0 + 64]       = h1;
    attA[base + DIM + c0 + 64] = l1;
    __syncthreads();
  }
}

// ---------------------------------------------------------------------------
extern "C" void kernel_launch(void* const* d_in, const int* in_sizes, int n_in,
                              void* d_out, int out_size, void* d_ws, size_t ws_size,
                              hipStream_t stream) {
  const float* x      = (const float*)d_in[0];
  const float* enc    = (const float*)d_in[1];
  const float* xmap   = (const float*)d_in[2];
  const float* q_w    = (const float*)d_in[3];
  const float* q_b    = (const float*)d_in[4];
  const float* kv_w   = (const float*)d_in[5];
  const float* kv_b   = (const float*)d_in[6];
  const float* proj_w = (const float*)d_in[7];
  const float* proj_b = (const float*)d_in[8];
  float* out = (float*)d_out;
  char* ws = (char*)d_ws;

  // workspace layout (bytes)
  const size_t OFF_POS  = 0;                           // 32760 f32
  const size_t OFF_APR  = 131072;                      // 32760 x 3072 bf16 (hi|lo)
  const size_t OFF_Q    = OFF_APR + 201277440;         // 32760 x 1536 f32
  const size_t OFF_KV   = OFF_Q   + 201277440;         // 672 x 3072 f32
  const size_t OFF_BQ   = OFF_KV  + 8257536;           // 1536 x 3072 bf16
  const size_t OFF_BKV  = OFF_BQ  + 9437184;           // 3072 x 1536 bf16
  const size_t OFF_BP   = OFF_BKV + 9437184;           // 1536 x 3072 bf16
  const size_t OFF_AKV  = OFF_BP  + 9437184;           // 672 x 1536 bf16
  const size_t TOTAL    = OFF_AKV + 2064384;           // ~421 MB
  if (ws_size < TOTAL) {
    fprintf(stderr, "kernel_launch: ws_size %zu < needed %zu\n", ws_size, TOTAL);
    return;
  }
  float*  pos   = (float*)(ws + OFF_POS);
  ushort* Apr   = (ushort*)(ws + OFF_APR);
  float*  qbuf  = (float*)(ws + OFF_Q);
  float*  kvbuf = (float*)(ws + OFF_KV);
  ushort* Bq    = (ushort*)(ws + OFF_BQ);
  ushort* Bkv   = (ushort*)(ws + OFF_BKV);
  ushort* Bp    = (ushort*)(ws + OFF_BP);
  ushort* Akv   = (ushort*)(ws + OFF_AKV);

  // 1) routing positions
  minmax_pos_kernel<<<1, 1024, 0, stream>>>(xmap, pos, TOK);
  // 2) hi/lo conversions
  conv_hilo_kernel<<<2048, 256, 0, stream>>>(x,      Apr, TOK,    DIM);
  conv_hilo_kernel<<<256,  256, 0, stream>>>(q_w,    Bq,  DIM,    DIM);
  conv_hilo_kernel<<<256,  256, 0, stream>>>(kv_w,   Bkv, 2*DIM,  ENCD);
  conv_hilo_kernel<<<64,   256, 0, stream>>>(enc,    Akv, KVROWS, ENCD);
  conv_hilo_kernel<<<256,  256, 0, stream>>>(proj_w, Bp,  DIM,    DIM);
  // 3) Q = x @ q_w^T + q_b   (256^2 8-phase)
  gemm256_bf16s_kernel<<<dim3(DIM/256, (TOK+255)/256), 512, 0, stream>>>(
      Apr, Bq, q_b, qbuf, TOK, DIM, DIM);
  // 4) KV = enc @ kv_w^T + kv_b  (tiny M: old 128^2 kernel fills grid better)
  gemm_bf16s_kernel<<<dim3(2*DIM/128, (KVROWS+127)/128), 256, 0, stream>>>(
      Akv, Bkv, kv_b, kvbuf, KVROWS, 2*DIM, ENCD);
  // 5) fused rope+attention, writes hi|lo att into Apr (x-conv dead by now)
  attn_kernel<<<dim3(52, HEADS, NT), 64, 0, stream>>>(qbuf, kvbuf, pos, Apr);
  // 6) out = att @ proj_w^T + proj_b  (256^2 8-phase)
  gemm256_bf16s_kernel<<<dim3(DIM/256, (TOK+255)/256), 512, 0, stream>>>(
      Apr, Bp, proj_b, out, TOK, DIM, DIM);
}

// Round 6
// 1699.480 us; speedup vs baseline: 1.1280x; 1.1280x over previous
//
#include <hip/hip_runtime.h>
#include <cstdio>
#include <cstdint>

// Problem constants (from setup_inputs; fixed for this problem)
#define TOK   32760      // N_t * S
#define DIM   1536
#define ENCD  768
#define NA    32
#define NT    21
#define SS    1560
#define HEADS 12
#define HD    128
#define KVROWS (NT * NA)   // 672

using f32x4  = __attribute__((ext_vector_type(4))) float;
using bf16x8 = __attribute__((ext_vector_type(8))) short;

__device__ __forceinline__ ushort bf16hi(float f) {
  unsigned u = __float_as_uint(f);
  return (ushort)((u + 0x7FFFu + ((u >> 16) & 1u)) >> 16);   // RNE
}
__device__ __forceinline__ float bf16tof(ushort h) {
  return __uint_as_float(((unsigned)h) << 16);
}

__device__ __forceinline__ void gload16(const void* g, void* l) {
  __builtin_amdgcn_global_load_lds((const __attribute__((address_space(1))) void*)g,
                                   (__attribute__((address_space(3))) void*)l,
                                   16, 0, 0);
}

// ---------------------------------------------------------------------------
// 1) min/max of the two attn-map rows + per-token rotary position
// ---------------------------------------------------------------------------
__global__ __launch_bounds__(1024) void minmax_pos_kernel(
    const float* __restrict__ m, float* __restrict__ pos, int N) {
  __shared__ float red[4][16];
  __shared__ float fin[4];
  int tid = threadIdx.x;
  float mn0 = 3.4e38f, mx0 = -3.4e38f, mn1 = 3.4e38f, mx1 = -3.4e38f;
  for (int i = tid; i < N; i += 1024) {
    float a = m[i], b = m[N + i];
    mn0 = fminf(mn0, a); mx0 = fmaxf(mx0, a);
    mn1 = fminf(mn1, b); mx1 = fmaxf(mx1, b);
  }
  #pragma unroll
  for (int o = 32; o >= 1; o >>= 1) {
    mn0 = fminf(mn0, __shfl_xor(mn0, o)); mx0 = fmaxf(mx0, __shfl_xor(mx0, o));
    mn1 = fminf(mn1, __shfl_xor(mn1, o)); mx1 = fmaxf(mx1, __shfl_xor(mx1, o));
  }
  int wid = tid >> 6, ln = tid & 63;
  if (ln == 0) { red[0][wid] = mn0; red[1][wid] = mx0; red[2][wid] = mn1; red[3][wid] = mx1; }
  __syncthreads();
  if (tid == 0) {
    float a = red[0][0], b = red[1][0], c = red[2][0], d = red[3][0];
    for (int i = 1; i < 16; i++) {
      a = fminf(a, red[0][i]); b = fmaxf(b, red[1][i]);
      c = fminf(c, red[2][i]); d = fmaxf(d, red[3][i]);
    }
    fin[0] = a; fin[1] = b; fin[2] = c; fin[3] = d;
  }
  __syncthreads();
  float mn0f = fin[0], sc0 = 4.0f / (fin[1] - fin[0] + 1e-8f);
  float mn1f = fin[2], sc1 = 4.0f / (fin[3] - fin[2] + 1e-8f);
  for (int i = tid; i < N; i += 1024) {
    float a = m[i], b = m[N + i];
    float h1 = (a - mn0f) * sc0;            // [0,4]
    float h2 = (b - mn1f) * sc1 + 20.0f;    // [20,24]
    pos[i] = (a >= b) ? h1 : h2;
  }
}

// ---------------------------------------------------------------------------
// 2) fp32 -> (bf16 hi | bf16 lo) split, rows of length K -> rows of length 2K
// ---------------------------------------------------------------------------
__global__ void conv_hilo_kernel(const float* __restrict__ in, ushort* __restrict__ out,
                                 int M, int K) {
  int total4 = M * (K / 4);
  for (int idx = blockIdx.x * blockDim.x + threadIdx.x; idx < total4;
       idx += gridDim.x * blockDim.x) {
    int e = idx * 4;
    int row = e / K;
    int k = e - row * K;
    float4 v = *(const float4*)(in + e);
    float fs[4] = {v.x, v.y, v.z, v.w};
    ushort hs[4], ls[4];
    #pragma unroll
    for (int t = 0; t < 4; t++) {
      hs[t] = bf16hi(fs[t]);
      float hf = bf16tof(hs[t]);
      ls[t] = bf16hi(fs[t] - hf);
    }
    ushort* po = out + (size_t)row * (2 * K) + k;
    *(ushort4*)(po)     = make_ushort4(hs[0], hs[1], hs[2], hs[3]);
    *(ushort4*)(po + K) = make_ushort4(ls[0], ls[1], ls[2], ls[3]);
  }
}

// ---------------------------------------------------------------------------
// 3a) OLD 128x128 1-phase split-bf16 GEMM — kept for the tiny KV GEMM (M=672)
//     where grid fill matters more than per-block efficiency.
// ---------------------------------------------------------------------------
__global__ __launch_bounds__(256, 2) void gemm_bf16s_kernel(
    const ushort* __restrict__ A, const ushort* __restrict__ B,
    const float* __restrict__ bias, float* __restrict__ C,
    int M, int N, int K) {
  __shared__ __align__(16) ushort lAh[128][64];
  __shared__ __align__(16) ushort lAl[128][64];
  __shared__ __align__(16) ushort lBh[128][64];
  __shared__ __align__(16) ushort lBl[128][64];
  const int tid = threadIdx.x;
  const int lane = tid & 63;
  const int w = tid >> 6;
  const int wm = w >> 1, wn = w & 1;
  const int quad = lane >> 4, m16 = lane & 15;
  const int r_off = lane >> 3;
  const int g     = lane & 7;
  const int gg8   = (g ^ r_off) * 8;

  int bx = blockIdx.x, by = blockIdx.y;
  {
    const int nx = gridDim.x, ny = gridDim.y;
    if ((ny & 7) == 0) {
      int flat = by * nx + bx;
      int xcd = flat & 7, s = flat >> 3;
      int panel = s / nx;
      bx = s - panel * nx;
      by = panel * 8 + xcd;
    }
  }
  const int m0 = by * 128, n0 = bx * 128;
  const int lda = 2 * K;

  f32x4 acc[4][4];
  #pragma unroll
  for (int i = 0; i < 4; i++)
    #pragma unroll
    for (int j = 0; j < 4; j++) acc[i][j] = (f32x4){0.f, 0.f, 0.f, 0.f};

  const int nIter = K / 64;
  for (int kt = 0; kt < nIter; kt++) {
    const int kH = kt * 64;
    const int kL = K + kt * 64;
    __syncthreads();
    #pragma unroll
    for (int i = 0; i < 4; i++) {
      const int ss = w * 4 + i;
      int rowA = m0 + ss * 8 + r_off; if (rowA >= M) rowA = M - 1;
      const ushort* ar = A + (size_t)rowA * lda;
      gload16(ar + kH + gg8, (char*)&lAh[0][0] + ss * 1024);
      gload16(ar + kL + gg8, (char*)&lAl[0][0] + ss * 1024);
      int rowB = n0 + ss * 8 + r_off; if (rowB >= N) rowB = N - 1;
      const ushort* br = B + (size_t)rowB * lda;
      gload16(br + kH + gg8, (char*)&lBh[0][0] + ss * 1024);
      gload16(br + kL + gg8, (char*)&lBl[0][0] + ss * 1024);
    }
    __syncthreads();
    #pragma unroll
    for (int kk = 0; kk < 2; kk++) {
      const int slot8 = (((kk * 4 + quad) ^ (m16 & 7)) * 8);
      bf16x8 fah[4], fbh[4], ft[4];
      #pragma unroll
      for (int i = 0; i < 4; i++) {
        fah[i] = *(const bf16x8*)(&lAh[wm * 64 + i * 16 + m16][slot8]);
        fbh[i] = *(const bf16x8*)(&lBh[wn * 64 + i * 16 + m16][slot8]);
      }
      #pragma unroll
      for (int i = 0; i < 4; i++)
        #pragma unroll
        for (int j = 0; j < 4; j++)
          acc[i][j] = __builtin_amdgcn_mfma_f32_16x16x32_bf16(fah[i], fbh[j], acc[i][j], 0, 0, 0);
      #pragma unroll
      for (int i = 0; i < 4; i++)
        ft[i] = *(const bf16x8*)(&lBl[wn * 64 + i * 16 + m16][slot8]);
      #pragma unroll
      for (int i = 0; i < 4; i++)
        #pragma unroll
        for (int j = 0; j < 4; j++)
          acc[i][j] = __builtin_amdgcn_mfma_f32_16x16x32_bf16(fah[i], ft[j], acc[i][j], 0, 0, 0);
      #pragma unroll
      for (int i = 0; i < 4; i++)
        ft[i] = *(const bf16x8*)(&lAl[wm * 64 + i * 16 + m16][slot8]);
      #pragma unroll
      for (int i = 0; i < 4; i++)
        #pragma unroll
        for (int j = 0; j < 4; j++)
          acc[i][j] = __builtin_amdgcn_mfma_f32_16x16x32_bf16(ft[i], fbh[j], acc[i][j], 0, 0, 0);
    }
  }
  #pragma unroll
  for (int j = 0; j < 4; j++) {
    const int col = n0 + wn * 64 + j * 16 + m16;
    const float bv = bias[col];
    #pragma unroll
    for (int i = 0; i < 4; i++) {
      const int rbase = m0 + wm * 64 + i * 16 + quad * 4;
      #pragma unroll
      for (int r = 0; r < 4; r++) {
        const int row = rbase + r;
        if (row < M) C[(size_t)row * N + col] = acc[i][j][r] + bv;
      }
    }
  }
}

// ---------------------------------------------------------------------------
// 3b) 256x256-tile split-bf16 GEMM, FULL-TILE single phase per K-step (R5).
//
// R5 post-mortem: the 4-phase (MH,NH)-quadrant ring measured MfmaUtil 32.5%
// (predicted 55-62).  Root cause: quadrant phases re-read every A fragment
// 2x (once per NH half) and every B fragment 2x (once per MH half) ->
// 48 ds_read_b128/wave/K-step = 393 KB/CU against 931 cyc of MFMA, plus 8
// barriers per K-step forcing LDS-burst/MFMA-burst serialization.
//
// New structure per K-step (BK=32, 8 waves, wave-tile 128x64):
//   [24 ds_read: ah[8],al[8],bh[4],bl[4] read ONCE]  (256 B/MFMA, was 512)
//   setprio(1); 96 MFMA (3 passes hi*hi, hi*lo, lo*hi); setprio(0)
//   lgkmcnt(0); barrier          // closes reads of buf bb
//   stage(s+2) -> buf bb          // 8 gload16/wave, region just freed
//   vmcnt(8); barrier             // stage(s+1) landed; keep s+2 in flight
// No intra-step barriers -> compiler software-pipelines ds_read into the
// MFMA stream with fine lgkmcnt (m97-verified behavior).  Counted vmcnt(8)
// keeps the 8 newest (step s+2) loads in flight across the barrier; stage
// (s+1) had one full compute-step (~3000 cyc >> 900 cyc HBM) in flight.
// LDS layout/swizzle unchanged from the R2-audited version:
// SA/SB[2][256][64 ush], granule slot XOR (row&7), gload source granule
// pre-swizzled (q = (lane&7)^rsel), fragment read slot = quad^(m16&7),
// lo half = slot^4 (ushort offset shq^32).
// ---------------------------------------------------------------------------
__global__ __launch_bounds__(512, 2) void gemm256_bf16s_kernel(
    const ushort* __restrict__ A, const ushort* __restrict__ B,
    const float* __restrict__ bias, float* __restrict__ C,
    int M, int N, int K) {
  __shared__ __align__(16) ushort SA[2][256][64];   // 64 KB
  __shared__ __align__(16) ushort SB[2][256][64];   // 64 KB
  const int tid  = threadIdx.x;
  const int lane = tid & 63;
  const int w    = tid >> 6;            // 0..7
  const int wm   = w >> 2, wn = w & 3;  // 2 x 4 wave grid
  const int quad = lane >> 4, m16 = lane & 15;
  const int rsel = lane >> 3;           // staging: row within 8-row group
  const int q    = (lane & 7) ^ rsel;   // staging: pre-swizzled source granule
  // XCD swizzle: all 6 column-tiles of a row panel land on one XCD's L2
  int bx = blockIdx.x, by = blockIdx.y;
  {
    const int nx = gridDim.x, ny = gridDim.y;
    if ((ny & 7) == 0) {
      int flat = by * nx + bx;
      int xcd = flat & 7, s = flat >> 3;
      int panel = s / nx;
      bx = s - panel * nx;
      by = panel * 8 + xcd;
    }
  }
  const int m0 = by * 256, n0 = bx * 256;
  const int ld   = 2 * K;
  const int qoff = (q & 3) * 8 + (q >> 2) * K;  // hi granules 0-3, lo 4-7
  const int shq  = (quad ^ (m16 & 7)) * 8;      // hi-slot ushort offset; lo = ^32

  auto stageA = [&](int st, int r0) {            // r0: tile row, multiple of 8
    int R = m0 + r0 + rsel; if (R >= M) R = M - 1;
    gload16(A + (size_t)R * ld + qoff + st * 32, &SA[st & 1][r0][0]);
  };
  auto stageB = [&](int st, int r0) {
    int R = n0 + r0 + rsel; if (R >= N) R = N - 1;
    gload16(B + (size_t)R * ld + qoff + st * 32, &SB[st & 1][r0][0]);
  };
  // full K-step stage: 8 gload16 per wave (A rows w*32..w*32+31, B same)
  auto stage = [&](int st) {
    #pragma unroll
    for (int t = 0; t < 4; t++) {
      stageA(st, w * 32 + t * 8);
      stageB(st, w * 32 + t * 8);
    }
  };

  f32x4 acc[8][4];
  #pragma unroll
  for (int i = 0; i < 8; i++)
    #pragma unroll
    for (int j = 0; j < 4; j++) acc[i][j] = (f32x4){0.f, 0.f, 0.f, 0.f};

  const int nS = K / 32;
  // prologue: stage step0 and step1; wait step0 only (keep step1 in flight)
  stage(0);
  if (nS > 1) {
    stage(1);
    asm volatile("s_waitcnt vmcnt(8)" ::: "memory");
  } else {
    asm volatile("s_waitcnt vmcnt(0)" ::: "memory");
  }
  __builtin_amdgcn_s_barrier();
  asm volatile("" ::: "memory");

  for (int s = 0; s < nS; s++) {
    const int bb = s & 1;
    bf16x8 ah[8], al[8], bh[4], bl[4];
    #pragma unroll
    for (int i = 0; i < 8; i++) {
      const ushort* ar = &SA[bb][wm * 128 + i * 16 + m16][0];
      ah[i] = *(const bf16x8*)(ar + shq);
      al[i] = *(const bf16x8*)(ar + (shq ^ 32));
    }
    #pragma unroll
    for (int j = 0; j < 4; j++) {
      const ushort* br = &SB[bb][wn * 64 + j * 16 + m16][0];
      bh[j] = *(const bf16x8*)(br + shq);
      bl[j] = *(const bf16x8*)(br + (shq ^ 32));
    }
    __builtin_amdgcn_s_setprio(1);
    #pragma unroll
    for (int i = 0; i < 8; i++)      // pass 1: Ahi x Bhi
      #pragma unroll
      for (int j = 0; j < 4; j++)
        acc[i][j] = __builtin_amdgcn_mfma_f32_16x16x32_bf16(ah[i], bh[j], acc[i][j], 0, 0, 0);
    #pragma unroll
    for (int i = 0; i < 8; i++)      // pass 2: Ahi x Blo
      #pragma unroll
      for (int j = 0; j < 4; j++)
        acc[i][j] = __builtin_amdgcn_mfma_f32_16x16x32_bf16(ah[i], bl[j], acc[i][j], 0, 0, 0);
    #pragma unroll
    for (int i = 0; i < 8; i++)      // pass 3: Alo x Bhi
      #pragma unroll
      for (int j = 0; j < 4; j++)
        acc[i][j] = __builtin_amdgcn_mfma_f32_16x16x32_bf16(al[i], bh[j], acc[i][j], 0, 0, 0);
    __builtin_amdgcn_s_setprio(0);
    asm volatile("s_waitcnt lgkmcnt(0)" ::: "memory");
    __builtin_amdgcn_s_barrier();            // all waves done reading buf bb
    asm volatile("" ::: "memory");
    if (s + 2 < nS) {
      stage(s + 2);                          // into bb (just freed)
      asm volatile("s_waitcnt vmcnt(8)" ::: "memory");  // s+1 landed, s+2 in flight
      __builtin_amdgcn_s_barrier();
      asm volatile("" ::: "memory");
    } else if (s + 1 < nS) {
      asm volatile("s_waitcnt vmcnt(0)" ::: "memory");
      __builtin_amdgcn_s_barrier();
      asm volatile("" ::: "memory");
    }
  }

  // epilogue: D row=(lane>>4)*4+reg, col=lane&15  [m89-verified layout]
  #pragma unroll
  for (int J = 0; J < 4; J++) {
    const int col = n0 + wn * 64 + J * 16 + m16;
    const float bv = bias[col];
    #pragma unroll
    for (int I = 0; I < 8; I++) {
      const int rbase = m0 + wm * 128 + I * 16 + quad * 4;
      #pragma unroll
      for (int r = 0; r < 4; r++) {
        const int row = rbase + r;
        if (row < M) C[(size_t)row * N + col] = acc[I][J][r] + bv;
      }
    }
  }
}

// ---------------------------------------------------------------------------
// 4) Fused attention: one wave per (t, head, 30-row chunk).
// ---------------------------------------------------------------------------
__global__ __launch_bounds__(64) void attn_kernel(
    const float* __restrict__ q, const float* __restrict__ kv,
    const float* __restrict__ pos, ushort* __restrict__ attA) {
  const int chunk = blockIdx.x;   // 0..51
  const int head  = blockIdx.y;   // 0..11
  const int t     = blockIdx.z;   // 0..20
  const int lane  = threadIdx.x;  // 0..63
  const int a = lane & 31, h = lane >> 5;
  const float L2_10000_64 = 13.287712379549449f / 64.0f;  // log2(10000)/64

  float kreg[64];
  const float* krow = kv + (size_t)(t * NA + a) * (2 * DIM) + head * HD + h * 64;
  #pragma unroll
  for (int j = 0; j < 16; j++) ((float4*)kreg)[j] = ((const float4*)krow)[j];
  const float pk = (a < 16) ? 2.0f : 22.0f;
  #pragma unroll
  for (int j = 0; j < 32; j++) {
    int ip = h * 32 + j;
    float fr = exp2f(-(float)ip * L2_10000_64);
    float sn, cs; sincosf(pk * fr, &sn, &cs);
    float x0 = kreg[2 * j], x1 = kreg[2 * j + 1];
    kreg[2 * j]     = x0 * cs - x1 * sn;
    kreg[2 * j + 1] = x1 * cs + x0 * sn;
  }
  float vr0[32], vr1[32];
  const float* vbase = kv + (size_t)(t * NA) * (2 * DIM) + DIM + head * HD;
  #pragma unroll
  for (int aa = 0; aa < 32; aa++) {
    vr0[aa] = vbase[(size_t)aa * (2 * DIM) + lane];
    vr1[aa] = vbase[(size_t)aa * (2 * DIM) + 64 + lane];
  }

  __shared__ float qs[128];
  __shared__ float Ps[32];
  const float myfreq = exp2f(-(float)lane * L2_10000_64);

  for (int r = 0; r < 30; r++) {
    const int n = t * SS + chunk * 30 + r;
    float2 qp = ((const float2*)(q + (size_t)n * DIM + head * HD))[lane];
    float p = pos[n];
    float sn, cs; sincosf(p * myfreq, &sn, &cs);
    qs[2 * lane]     = qp.x * cs - qp.y * sn;
    qs[2 * lane + 1] = qp.y * cs + qp.x * sn;
    __syncthreads();
    float accd = 0.f;
    #pragma unroll
    for (int j4 = 0; j4 < 16; j4++) {
      float4 qq = ((const float4*)(qs + h * 64))[j4];
      accd += qq.x * kreg[j4 * 4] + qq.y * kreg[j4 * 4 + 1] +
              qq.z * kreg[j4 * 4 + 2] + qq.w * kreg[j4 * 4 + 3];
    }
    accd += __shfl_xor(accd, 32);
    accd *= 0.08838834764831845f;    // 1/sqrt(128)
    float mx = accd;
    #pragma unroll
    for (int o = 16; o >= 1; o >>= 1) mx = fmaxf(mx, __shfl_xor(mx, o));
    float e = __expf(accd - mx);
    float sum = e;
    #pragma unroll
    for (int o = 16; o >= 1; o >>= 1) sum += __shfl_xor(sum, o);
    float P = e / sum;
    if (lane < 32) Ps[lane] = P;
    __syncthreads();
    float o0 = 0.f, o1 = 0.f;
    #pragma unroll
    for (int aa = 0; aa < 32; aa++) {
      float pa = Ps[aa];
      o0 += pa * vr0[aa];
      o1 += pa * vr1[aa];
    }
    size_t base = (size_t)n * (2 * DIM);
    int c0 = head * HD + lane;
    ushort h0 = bf16hi(o0); ushort l0 = bf16hi(o0 - bf16tof(h0));
    ushort h1 = bf16hi(o1); ushort l1 = bf16hi(o1 - bf16tof(h1));
    attA[base + c0]            = h0;
    attA[base + DIM + c0]      = l0;
    attA[base + c0 + 64]       = h1;
    attA[base + DIM + c0 + 64] = l1;
    __syncthreads();
  }
}

// ---------------------------------------------------------------------------
extern "C" void kernel_launch(void* const* d_in, const int* in_sizes, int n_in,
                              void* d_out, int out_size, void* d_ws, size_t ws_size,
                              hipStream_t stream) {
  const float* x      = (const float*)d_in[0];
  const float* enc    = (const float*)d_in[1];
  const float* xmap   = (const float*)d_in[2];
  const float* q_w    = (const float*)d_in[3];
  const float* q_b    = (const float*)d_in[4];
  const float* kv_w   = (const float*)d_in[5];
  const float* kv_b   = (const float*)d_in[6];
  const float* proj_w = (const float*)d_in[7];
  const float* proj_b = (const float*)d_in[8];
  float* out = (float*)d_out;
  char* ws = (char*)d_ws;

  // workspace layout (bytes)
  const size_t OFF_POS  = 0;                           // 32760 f32
  const size_t OFF_APR  = 131072;                      // 32760 x 3072 bf16 (hi|lo)
  const size_t OFF_Q    = OFF_APR + 201277440;         // 32760 x 1536 f32
  const size_t OFF_KV   = OFF_Q   + 201277440;         // 672 x 3072 f32
  const size_t OFF_BQ   = OFF_KV  + 8257536;           // 1536 x 3072 bf16
  const size_t OFF_BKV  = OFF_BQ  + 9437184;           // 3072 x 1536 bf16
  const size_t OFF_BP   = OFF_BKV + 9437184;           // 1536 x 3072 bf16
  const size_t OFF_AKV  = OFF_BP  + 9437184;           // 672 x 1536 bf16
  const size_t TOTAL    = OFF_AKV + 2064384;           // ~421 MB
  if (ws_size < TOTAL) {
    fprintf(stderr, "kernel_launch: ws_size %zu < needed %zu\n", ws_size, TOTAL);
    return;
  }
  float*  pos   = (float*)(ws + OFF_POS);
  ushort* Apr   = (ushort*)(ws + OFF_APR);
  float*  qbuf  = (float*)(ws + OFF_Q);
  float*  kvbuf = (float*)(ws + OFF_KV);
  ushort* Bq    = (ushort*)(ws + OFF_BQ);
  ushort* Bkv   = (ushort*)(ws + OFF_BKV);
  ushort* Bp    = (ushort*)(ws + OFF_BP);
  ushort* Akv   = (ushort*)(ws + OFF_AKV);

  // 1) routing positions
  minmax_pos_kernel<<<1, 1024, 0, stream>>>(xmap, pos, TOK);
  // 2) hi/lo conversions
  conv_hilo_kernel<<<2048, 256, 0, stream>>>(x,      Apr, TOK,    DIM);
  conv_hilo_kernel<<<256,  256, 0, stream>>>(q_w,    Bq,  DIM,    DIM);
  conv_hilo_kernel<<<256,  256, 0, stream>>>(kv_w,   Bkv, 2*DIM,  ENCD);
  conv_hilo_kernel<<<64,   256, 0, stream>>>(enc,    Akv, KVROWS, ENCD);
  conv_hilo_kernel<<<256,  256, 0, stream>>>(proj_w, Bp,  DIM,    DIM);
  // 3) Q = x @ q_w^T + q_b   (256^2 full-tile phase)
  gemm256_bf16s_kernel<<<dim3(DIM/256, (TOK+255)/256), 512, 0, stream>>>(
      Apr, Bq, q_b, qbuf, TOK, DIM, DIM);
  // 4) KV = enc @ kv_w^T + kv_b  (tiny M: old 128^2 kernel fills grid better)
  gemm_bf16s_kernel<<<dim3(2*DIM/128, (KVROWS+127)/128), 256, 0, stream>>>(
      Akv, Bkv, kv_b, kvbuf, KVROWS, 2*DIM, ENCD);
  // 5) fused rope+attention, writes hi|lo att into Apr (x-conv dead by now)
  attn_kernel<<<dim3(52, HEADS, NT), 64, 0, stream>>>(qbuf, kvbuf, pos, Apr);
  // 6) out = att @ proj_w^T + proj_b  (256^2 full-tile phase)
  gemm256_bf16s_kernel<<<dim3(DIM/256, (TOK+255)/256), 512, 0, stream>>>(
      Apr, Bp, proj_b, out, TOK, DIM, DIM);
}